// Round 1
// baseline (133.318 us; speedup 1.0000x reference)
//
#include <hip/hip_runtime.h>
#include <hip/hip_bf16.h>

typedef __attribute__((ext_vector_type(8))) short short8;
typedef __attribute__((ext_vector_type(4))) float f32x4;

static constexpr int IN = 32, OUT = 32, DYNDIM = 16, KNBR = 7;

__device__ inline unsigned short f2bf(float f) {
    unsigned u = __builtin_bit_cast(unsigned, f);
    // round-to-nearest-even (inputs finite)
    unsigned r = (u + 0x7fffu + ((u >> 16) & 1u)) >> 16;
    return (unsigned short)r;
}

// Kernel 1: Wcomb[b,k,i,o] = sum_d dyn[b,k,d]*Wdyn[k,d,i,o] + Wstatic[k,i,o]
// packed as bf16 into B-fragment layout: Wp[b][k][ch][lane][j]
//   ch = o>>4, lane = (i>>3)*16 + (o&15), j = i&7
__global__ void pack_weights(const float* __restrict__ dyn,    // (B,7,16)
                             const float* __restrict__ Wdyn,   // (7,16,32,32)
                             const float* __restrict__ Wstat,  // (7,32,32)
                             unsigned short* __restrict__ Wp)  // (B,7,2,64,8)
{
    int bk = blockIdx.x;              // b*7 + k
    int k  = bk % KNBR;
    __shared__ float dsh[DYNDIM];
    if (threadIdx.x < DYNDIM)
        dsh[threadIdx.x] = dyn[(size_t)bk * DYNDIM + threadIdx.x];
    __syncthreads();

    for (int e = threadIdx.x; e < IN * OUT; e += blockDim.x) {
        int i = e >> 5, o = e & 31;
        float acc = Wstat[((size_t)k * IN + i) * OUT + o];
        const float* wd = Wdyn + (((size_t)k * DYNDIM) * IN + i) * OUT + o;
#pragma unroll
        for (int d = 0; d < DYNDIM; ++d)
            acc += dsh[d] * wd[(size_t)d * IN * OUT];
        int ch = o >> 4, c = o & 15, g = i >> 3, j = i & 7;
        Wp[(((size_t)bk * 2 + ch) * 64 + (g * 16 + c)) * 8 + j] = f2bf(acc);
    }
}

// Kernel 2: per wave, 16 rows x 32 cols via 7x2 MFMA 16x16x32 bf16.
__global__ __launch_bounds__(256) void hexconv(
    const float* __restrict__ grid,        // (B,N,32) f32
    const int* __restrict__ nbr,           // (7,N)
    const unsigned short* __restrict__ Wp, // (B,7,2,64,8) bf16
    const float* __restrict__ bias,        // (32)
    float* __restrict__ out,               // (B,N,32) f32
    int N)
{
    const int b    = blockIdx.y;
    const int lane = threadIdx.x & 63;
    const int w    = threadIdx.x >> 6;          // wave 0..3
    const int g    = lane >> 4;                 // lane group 0..3
    const int c    = lane & 15;

    const int n0 = blockIdx.x * 64 + w * 16 + c;   // A-fragment row for this lane
    const size_t gbase = (size_t)b * N * 32;
    const unsigned short* wpb = Wp + (size_t)b * KNBR * 2 * 512;

    f32x4 acc0 = {0.f, 0.f, 0.f, 0.f};
    f32x4 acc1 = {0.f, 0.f, 0.f, 0.f};

#pragma unroll
    for (int kk = 0; kk < KNBR; ++kk) {
        int idx = (n0 < N) ? nbr[(size_t)kk * N + n0] : -1;
        short8 a = {0, 0, 0, 0, 0, 0, 0, 0};
        if (idx >= 0) {
            const float* gp = grid + gbase + (size_t)idx * 32 + g * 8;
            float4 x0 = *(const float4*)gp;
            float4 x1 = *(const float4*)(gp + 4);
            a[0] = (short)f2bf(x0.x); a[1] = (short)f2bf(x0.y);
            a[2] = (short)f2bf(x0.z); a[3] = (short)f2bf(x0.w);
            a[4] = (short)f2bf(x1.x); a[5] = (short)f2bf(x1.y);
            a[6] = (short)f2bf(x1.z); a[7] = (short)f2bf(x1.w);
        }
        const unsigned short* wk = wpb + (size_t)kk * 2 * 512;
        short8 b0 = *(const short8*)(wk + lane * 8);
        short8 b1 = *(const short8*)(wk + 512 + lane * 8);
        acc0 = __builtin_amdgcn_mfma_f32_16x16x32_bf16(a, b0, acc0, 0, 0, 0);
        acc1 = __builtin_amdgcn_mfma_f32_16x16x32_bf16(a, b1, acc1, 0, 0, 0);
    }

    const float bc0 = bias[c];
    const float bc1 = bias[16 + c];
    const int row_base = blockIdx.x * 64 + w * 16 + g * 4;
#pragma unroll
    for (int r = 0; r < 4; ++r) {
        int row = row_base + r;
        if (row < N) {
            float* op = out + gbase + (size_t)row * 32;
            op[c]      = acc0[r] + bc0;
            op[16 + c] = acc1[r] + bc1;
        }
    }
}

extern "C" void kernel_launch(void* const* d_in, const int* in_sizes, int n_in,
                              void* d_out, int out_size, void* d_ws, size_t ws_size,
                              hipStream_t stream)
{
    const float* grid  = (const float*)d_in[0];
    const float* dyn   = (const float*)d_in[1];
    const int*   nbr   = (const int*)d_in[2];
    const float* Wdyn  = (const float*)d_in[3];
    const float* Wstat = (const float*)d_in[4];
    const float* bias  = (const float*)d_in[5];
    float* out = (float*)d_out;

    const int N = in_sizes[2] / KNBR;               // 27361
    const int B = in_sizes[0] / (N * IN);           // 32

    unsigned short* Wp = (unsigned short*)d_ws;     // B*7*2*64*8 bf16 = 458752 B

    pack_weights<<<B * KNBR, 256, 0, stream>>>(dyn, Wdyn, Wstat, Wp);

    dim3 grd((N + 63) / 64, B);
    hexconv<<<grd, 256, 0, stream>>>(grid, nbr, Wp, bias, out, N);
}